// Round 3
// baseline (286.215 us; speedup 1.0000x reference)
//
#include <hip/hip_runtime.h>

#define NN 4096
#define DD 256
#define EE 131072

typedef __attribute__((ext_vector_type(8))) short s16x8;
typedef __attribute__((ext_vector_type(4))) float f32x4;

__device__ __forceinline__ unsigned short f2bf(float f) {
  unsigned u = __builtin_bit_cast(unsigned, f);
  u += 0x7FFFu + ((u >> 16) & 1u);
  return (unsigned short)(u >> 16);
}

__device__ __forceinline__ ushort4 cvt4(f32x4 v) {
  ushort4 r;
  r.x = f2bf(v[0]); r.y = f2bf(v[1]); r.z = f2bf(v[2]); r.w = f2bf(v[3]);
  return r;
}

// round-half-up fp32->bf16 pair pack: 2 adds + 1 v_perm
__device__ __forceinline__ unsigned cvt2_rhu(float a, float b) {
  unsigned ua = __builtin_bit_cast(unsigned, a) + 0x8000u;
  unsigned ub = __builtin_bit_cast(unsigned, b) + 0x8000u;
  return __builtin_amdgcn_perm(ub, ua, 0x07060302u);
}

__device__ __forceinline__ uint4 pack8(f32x4 a, f32x4 b) {
  uint4 r;
  r.x = cvt2_rhu(a[0], a[1]); r.y = cvt2_rhu(a[2], a[3]);
  r.z = cvt2_rhu(b[0], b[1]); r.w = cvt2_rhu(b[2], b[3]);
  return r;
}

// B fragment layout (consumed by mfma_16x16x32_bf16 B-operand):
//   element (n, k) lives at ushort index
//   (tile*128 + kc)*512 + (quad*16 + (n&15))*8 + (k&7)
//   tile = n>>4, kc = k>>5, quad = (k>>3)&3. One wave chunk-load = 1KB coalesced.

// ---------------------------------------------------------------------------
// K1: count in-degrees + write both W matrices in B-fragment layout (bf16)
// ---------------------------------------------------------------------------
__global__ void k_prep(const int* __restrict__ ei, int* __restrict__ deg,
                       const float* __restrict__ Wh, const float* __restrict__ Wc,
                       unsigned short* __restrict__ WFh, unsigned short* __restrict__ WFc) {
  int t = blockIdx.x * 256 + threadIdx.x;
  if (t < EE) {
    atomicAdd(&deg[ei[EE + t]], 1);
  } else {
    int idx = t - EE;
    int which = idx >> 16;
    int r = idx & 65535;
    int n = r & 255, k = r >> 8;
    const float* W = which ? Wc : Wh;
    unsigned short* WF = which ? WFc : WFh;
    long fidx = ((long)((n >> 4) * 8 + (k >> 5))) * 512 +
                (((k >> 3) & 3) * 16 + (n & 15)) * 8 + (k & 7);
    WF[fidx] = f2bf(W[k * 256 + n]);
  }
}

// ---------------------------------------------------------------------------
// K2: exclusive scan of deg -> row_start[4097]; dis = rsqrt(deg+1)
// ---------------------------------------------------------------------------
__global__ void k_scan(const int* __restrict__ deg, int* __restrict__ row_start,
                       float* __restrict__ dis) {
  __shared__ int part[1024];
  int t = threadIdx.x;
  int d0 = deg[4 * t + 0], d1 = deg[4 * t + 1], d2 = deg[4 * t + 2], d3 = deg[4 * t + 3];
  int s = d0 + d1 + d2 + d3;
  part[t] = s;
  __syncthreads();
  for (int off = 1; off < 1024; off <<= 1) {
    int add = (t >= off) ? part[t - off] : 0;
    __syncthreads();
    part[t] += add;
    __syncthreads();
  }
  int base = part[t] - s;
  row_start[4 * t + 0] = base;
  row_start[4 * t + 1] = base + d0;
  row_start[4 * t + 2] = base + d0 + d1;
  row_start[4 * t + 3] = base + d0 + d1 + d2;
  if (t == 1023) row_start[4096] = part[t];
  dis[4 * t + 0] = rsqrtf((float)d0 + 1.0f);
  dis[4 * t + 1] = rsqrtf((float)d1 + 1.0f);
  dis[4 * t + 2] = rsqrtf((float)d2 + 1.0f);
  dis[4 * t + 3] = rsqrtf((float)d3 + 1.0f);
}

// ---------------------------------------------------------------------------
// K3: scatter edges into CSR buckets
// ---------------------------------------------------------------------------
__global__ void k_scatter(const int* __restrict__ ei, const int* __restrict__ row_start,
                          int* __restrict__ cursor, int* __restrict__ csr) {
  int e = blockIdx.x * 256 + threadIdx.x;
  if (e < EE) {
    int s = ei[e];
    int d = ei[EE + e];
    int p = atomicAdd(&cursor[d], 1);
    csr[row_start[d] + p] = s;
  }
}

// ---------------------------------------------------------------------------
// K4: RF = frag(relu(x @ W_high))  and  XWs[m][n] = dis[m] * (x @ W_conv)[m][n]
// ---------------------------------------------------------------------------
__global__ __launch_bounds__(512) void k_xw(const float* __restrict__ x,
                                            const unsigned short* __restrict__ WFh,
                                            const unsigned short* __restrict__ WFc,
                                            unsigned short* __restrict__ RF,
                                            float* __restrict__ XWs,
                                            const float* __restrict__ dis) {
  __shared__ alignas(16) unsigned short Abuf[16][264];
  const int tid = threadIdx.x;
  const int w = tid >> 6, lane = tid & 63;
  const int quad = lane >> 4, l16 = lane & 15, quad8 = quad * 8;
  const int m0 = blockIdx.x * 16;

  {
    int srow = tid >> 5, scolf = (tid & 31) * 8;
    const float* ap = x + (long)(m0 + srow) * DD + scolf;
    f32x4 a0 = *(const f32x4*)ap;
    f32x4 a1 = *(const f32x4*)(ap + 4);
    *(uint4*)&Abuf[srow][scolf] = pack8(a0, a1);
  }
  __syncthreads();

  const bool hi = (w < 4);
  const int wo = hi ? w : (w - 4);
  const unsigned short* WF = hi ? WFh : WFc;
  const unsigned short* bp = WF + lane * 8;

  f32x4 acc[4] = {{0,0,0,0},{0,0,0,0},{0,0,0,0},{0,0,0,0}};
#pragma unroll
  for (int q = 0; q < 8; ++q) {
    s16x8 af = *(const s16x8*)&Abuf[l16][q * 32 + quad8];
#pragma unroll
    for (int s = 0; s < 4; ++s) {
      s16x8 bf = *(const s16x8*)(bp + ((long)((4 * wo + s) * 8 + q)) * 512);
      acc[s] = __builtin_amdgcn_mfma_f32_16x16x32_bf16(af, bf, acc[s], 0, 0, 0);
    }
  }

  if (hi) {
    const int kc = m0 >> 5;
    const int qp = ((m0 >> 4) & 1) * 2 + (quad >> 1);
    const int j0 = (quad & 1) * 4;
#pragma unroll
    for (int s = 0; s < 4; ++s) {
      int t = 4 * wo + s;
      f32x4 v = acc[s];
      f32x4 z;
      z[0] = v[0] > 0.f ? v[0] : 0.f;
      z[1] = v[1] > 0.f ? v[1] : 0.f;
      z[2] = v[2] > 0.f ? v[2] : 0.f;
      z[3] = v[3] > 0.f ? v[3] : 0.f;
      long idx = ((long)(t * 128 + kc)) * 512 + (qp * 16 + l16) * 8 + j0;
      *(ushort4*)(RF + idx) = cvt4(z);
    }
  } else {
    float dm[4];
#pragma unroll
    for (int r = 0; r < 4; ++r) dm[r] = dis[m0 + quad * 4 + r];
#pragma unroll
    for (int s = 0; s < 4; ++s) {
      int col = 64 * wo + 16 * s + l16;
#pragma unroll
      for (int r = 0; r < 4; ++r)
        XWs[(long)(m0 + quad * 4 + r) * DD + col] = dm[r] * acc[s][r];
    }
  }
}

// ---------------------------------------------------------------------------
// K5: GCN aggregation, dis pre-multiplied into XWs; unroll-by-8 gathers
// ---------------------------------------------------------------------------
__global__ void k_agg(const float* __restrict__ XWs, const int* __restrict__ row_start,
                      const int* __restrict__ csr, const float* __restrict__ dis,
                      float* __restrict__ Hl) {
  const int i = blockIdx.x;
  const int t = threadIdx.x;
  const int b0 = row_start[i], b1 = row_start[i + 1];
  float acc = XWs[(long)i * DD + t];
  int j = b0;
  for (; j + 8 <= b1; j += 8) {
    int s0 = csr[j], s1 = csr[j + 1], s2 = csr[j + 2], s3 = csr[j + 3];
    int s4 = csr[j + 4], s5 = csr[j + 5], s6 = csr[j + 6], s7 = csr[j + 7];
    float v0 = XWs[(long)s0 * DD + t];
    float v1 = XWs[(long)s1 * DD + t];
    float v2 = XWs[(long)s2 * DD + t];
    float v3 = XWs[(long)s3 * DD + t];
    float v4 = XWs[(long)s4 * DD + t];
    float v5 = XWs[(long)s5 * DD + t];
    float v6 = XWs[(long)s6 * DD + t];
    float v7 = XWs[(long)s7 * DD + t];
    acc += ((v0 + v1) + (v2 + v3)) + ((v4 + v5) + (v6 + v7));
  }
  for (; j < b1; ++j) acc += XWs[(long)csr[j] * DD + t];
  Hl[(long)i * DD + t] = dis[i] * acc;
}

// ---------------------------------------------------------------------------
// K6: C[4096 x 256] = A[4096 x 4096](fp32) @ B (bf16 fragment layout).
//     Re-tiled for 2 blocks/CU: grid 512 = q*128 + m (q = N-quarter, m = M-tile);
//     quarter-siblings {m, 128+m, 256+m, 384+m} -> same XCD (128 % 8 == 0),
//     co-resident -> A re-reads are L2 hits. Block 256 = 4 waves; wave owns
//     n-tile (q*4+w), 2 M-subtiles (acc[2]). 16 K-stages of 256, LDS dbuf,
//     depth-1 A reg prefetch, B reg ping-pong (s+1 loaded during s compute).
//     EPI 0: write C in fragment layout (next mm's B).  EPI 3: fused final.
// ---------------------------------------------------------------------------
#define MM3_STEP(sv, BCUR, BNXT, CUR, NXT)                                        \
  {                                                                               \
    const int sn = (sv) + 1;                                                      \
    f32x4 an[8];                                                                  \
    if (sn < 16) {                                                                \
      _Pragma("unroll")                                                           \
      for (int i = 0; i < 4; ++i) {                                               \
        an[i] = *(const f32x4*)(aptr0 + sn * 256 + 4 * i);                        \
        an[4 + i] = *(const f32x4*)(aptr1 + sn * 256 + 4 * i);                    \
      }                                                                           \
      _Pragma("unroll")                                                           \
      for (int c8 = 0; c8 < 8; ++c8)                                              \
        BNXT[c8] = *(const s16x8*)(bbase + ((long)(sn * 8 + c8)) * 512);          \
    }                                                                             \
    _Pragma("unroll")                                                             \
    for (int c8 = 0; c8 < 8; ++c8) {                                              \
      s16x8 a0 = *(const s16x8*)&Abuf[CUR][l16][c8 * 32 + quad8];                 \
      s16x8 a1 = *(const s16x8*)&Abuf[CUR][16 + l16][c8 * 32 + quad8];            \
      acc[0] = __builtin_amdgcn_mfma_f32_16x16x32_bf16(a0, BCUR[c8], acc[0], 0, 0, 0); \
      acc[1] = __builtin_amdgcn_mfma_f32_16x16x32_bf16(a1, BCUR[c8], acc[1], 0, 0, 0); \
    }                                                                             \
    if (sn < 16) {                                                                \
      *(uint4*)&Abuf[NXT][arow][acolf] = pack8(an[0], an[1]);                     \
      *(uint4*)&Abuf[NXT][arow][acolf + 8] = pack8(an[2], an[3]);                 \
      *(uint4*)&Abuf[NXT][arow + 16][acolf] = pack8(an[4], an[5]);                \
      *(uint4*)&Abuf[NXT][arow + 16][acolf + 8] = pack8(an[6], an[7]);            \
    }                                                                             \
    __syncthreads();                                                              \
  }

template <int EPI>
__global__ __launch_bounds__(256) void k_mm3(const float* __restrict__ A,
                                             const unsigned short* __restrict__ BF,
                                             unsigned short* __restrict__ CF,
                                             float* __restrict__ outF,
                                             const float* __restrict__ Hl,
                                             const float* __restrict__ bconv,
                                             const float* __restrict__ aLp,
                                             const float* __restrict__ aHp) {
  __shared__ alignas(16) unsigned short Abuf[2][32][264];
  const int tid = threadIdx.x;
  const int w = tid >> 6, lane = tid & 63;
  const int quad = lane >> 4, l16 = lane & 15, quad8 = quad * 8;
  const int m = blockIdx.x & 127;
  const int q = blockIdx.x >> 7;
  const int m0 = m * 32;
  const int tglob = q * 4 + w;

  const int arow = tid >> 4;           // 0..15 (also handles arow+16)
  const int acolf = (tid & 15) * 16;   // col (floats == ushorts index)
  const float* aptr0 = A + (long)(m0 + arow) * NN + acolf;
  const float* aptr1 = aptr0 + (long)16 * NN;

  const unsigned short* bbase = BF + ((long)tglob * 128) * 512 + lane * 8;

  f32x4 acc[2] = {{0,0,0,0},{0,0,0,0}};
  s16x8 bbA[8], bbB[8];

  // prologue: A stage 0 -> LDS, B stage 0 -> bbA
  {
    f32x4 r0 = *(const f32x4*)(aptr0 + 0);
    f32x4 r1 = *(const f32x4*)(aptr0 + 4);
    f32x4 r2 = *(const f32x4*)(aptr0 + 8);
    f32x4 r3 = *(const f32x4*)(aptr0 + 12);
    f32x4 r4 = *(const f32x4*)(aptr1 + 0);
    f32x4 r5 = *(const f32x4*)(aptr1 + 4);
    f32x4 r6 = *(const f32x4*)(aptr1 + 8);
    f32x4 r7 = *(const f32x4*)(aptr1 + 12);
    *(uint4*)&Abuf[0][arow][acolf] = pack8(r0, r1);
    *(uint4*)&Abuf[0][arow][acolf + 8] = pack8(r2, r3);
    *(uint4*)&Abuf[0][arow + 16][acolf] = pack8(r4, r5);
    *(uint4*)&Abuf[0][arow + 16][acolf + 8] = pack8(r6, r7);
  }
#pragma unroll
  for (int c8 = 0; c8 < 8; ++c8) bbA[c8] = *(const s16x8*)(bbase + c8 * 512);
  __syncthreads();

  for (int ss = 0; ss < 8; ++ss) {
    MM3_STEP(2 * ss, bbA, bbB, 0, 1)
    MM3_STEP(2 * ss + 1, bbB, bbA, 1, 0)
  }

  if constexpr (EPI == 0) {
    // frag(n = tglob*16+l16, k = m0 + mu*16 + quad*4 + r)
#pragma unroll
    for (int mu = 0; mu < 2; ++mu) {
      int qp = mu * 2 + (quad >> 1);
      int j0 = (quad & 1) * 4;
      long idx = ((long)(tglob * 128 + m)) * 512 + (qp * 16 + l16) * 8 + j0;
      *(ushort4*)(CF + idx) = cvt4(acc[mu]);
    }
  } else {
    __shared__ float obuf[32][68];
#pragma unroll
    for (int mu = 0; mu < 2; ++mu)
#pragma unroll
      for (int r = 0; r < 4; ++r)
        obuf[mu * 16 + quad * 4 + r][w * 16 + l16] = acc[mu][r];
    __syncthreads();
    const float aLv = aLp[0], aHv = aHp[0];
    const int orow = tid >> 3;           // 0..31
    const int ocol = (tid & 7) * 8;      // 0..56
    const int gcol = q * 64 + ocol;
#pragma unroll
    for (int j = 0; j < 2; ++j) {
      f32x4 cc = *(const f32x4*)&obuf[orow][ocol + 4 * j];
      f32x4 h = *(const f32x4*)(Hl + (long)(m0 + orow) * DD + gcol + 4 * j);
      f32x4 bc = *(const f32x4*)(bconv + gcol + 4 * j);
      f32x4 res;
      res[0] = aHv * cc[0] + aLv * (h[0] + bc[0]);
      res[1] = aHv * cc[1] + aLv * (h[1] + bc[1]);
      res[2] = aHv * cc[2] + aLv * (h[2] + bc[2]);
      res[3] = aHv * cc[3] + aLv * (h[3] + bc[3]);
      *(f32x4*)(outF + (long)(m0 + orow) * DD + gcol + 4 * j) = res;
    }
  }
}

// ---------------------------------------------------------------------------
// launcher
// ---------------------------------------------------------------------------
extern "C" void kernel_launch(void* const* d_in, const int* in_sizes, int n_in,
                              void* d_out, int out_size, void* d_ws, size_t ws_size,
                              hipStream_t stream) {
  const float* x     = (const float*)d_in[0];
  const int*   ei    = (const int*)d_in[1];
  const float* lap   = (const float*)d_in[2];
  const float* dinv  = (const float*)d_in[3];
  const float* Wh    = (const float*)d_in[4];
  const float* Wc    = (const float*)d_in[5];
  const float* bconv = (const float*)d_in[6];
  const float* aL    = (const float*)d_in[7];
  const float* aH    = (const float*)d_in[8];
  float* out = (float*)d_out;
  char* ws = (char*)d_ws;

  int* deg        = (int*)(ws);
  int* cursor     = (int*)(ws + (16 << 10));
  int* row_start  = (int*)(ws + (32 << 10));
  int* csr        = (int*)(ws + (64 << 10));
  float* dis      = (float*)(ws + (576 << 10));
  unsigned short* WFh = (unsigned short*)(ws + (1l << 20));
  unsigned short* WFc = (unsigned short*)(ws + (1l << 20) + (128 << 10));
  unsigned short* RF  = (unsigned short*)(ws + (2l << 20));
  unsigned short* T1F = (unsigned short*)(ws + (4l << 20));
  unsigned short* T2F = (unsigned short*)(ws + (6l << 20));
  float* XWs = (float*)(ws + (8l << 20));
  float* Hl  = (float*)(ws + (12l << 20));

  hipMemsetAsync(ws, 0, 32 << 10, stream);   // deg + cursor

  k_prep<<<1024, 256, 0, stream>>>(ei, deg, Wh, Wc, WFh, WFc);
  k_scan<<<1, 1024, 0, stream>>>(deg, row_start, dis);
  k_scatter<<<512, 256, 0, stream>>>(ei, row_start, cursor, csr);
  k_xw<<<256, 512, 0, stream>>>(x, WFh, WFc, RF, XWs, dis);
  k_agg<<<4096, 256, 0, stream>>>(XWs, row_start, csr, dis, Hl);

  k_mm3<0><<<512, 256, 0, stream>>>(dinv, RF, T1F, nullptr, nullptr, nullptr, nullptr, nullptr);
  k_mm3<0><<<512, 256, 0, stream>>>(lap, T1F, T2F, nullptr, nullptr, nullptr, nullptr, nullptr);
  k_mm3<3><<<512, 256, 0, stream>>>(dinv, T2F, nullptr, out, Hl, bconv, aL, aH);
}